// Round 21
// baseline (883.233 us; speedup 1.0000x reference)
//
#include <hip/hip_runtime.h>
#include <hip/hip_bf16.h>

// BitNet FFN: LN -> act_quant/ternary-W matmul -> GELU(erf) -> act_quant/ternary-W matmul
// Shapes: x[4,4096,2048] f32, w1[8192,2048], w2[2048,8192], out [16384,2048] f32.
// R21 = R20 minus the dead mis-typed helper (compile fix; no functional change).
// R19 (64x64/wave, 4 waves/SIMD, 2 blocks/CU) + TRIPLE-BUFFERED A: A(t+2)
// staged in Pa(t) -> 4-phase (~1200cyc) lead >= HBM/L3 latency (R19 exposed
// ~300-600cyc/iter waiting on A staged 1 phase earlier). B (L2-resident wq)
// keeps 2-phase lead. Single-queue vmcnt(3) ledger (all stages global_load_lds).
// LDS 64KB (A 3x16K + B 2x8K), 2 blocks/CU.
// i8 MFMA 16x16x64; i32 accum exact -> output bit-identical (absmax 2.539e-2).
// Peak ws 193 MiB; d_out doubles as f32 GELU staging per M-chunk.

typedef __attribute__((ext_vector_type(4))) int int4v;

#define D_DIM 2048
#define H_DIM 8192
#define M_DIM 16384
#define MCHUNK 4096

// ---------- small helpers ----------
__device__ __forceinline__ float block_sum(float v, float* buf) {
#pragma unroll
  for (int o = 32; o > 0; o >>= 1) v += __shfl_down(v, o, 64);
  const int lane = threadIdx.x & 63, w = threadIdx.x >> 6;
  if (lane == 0) buf[w] = v;
  __syncthreads();
  float r = buf[0] + buf[1] + buf[2] + buf[3];
  __syncthreads();
  return r;
}
__device__ __forceinline__ float block_max(float v, float* buf) {
#pragma unroll
  for (int o = 32; o > 0; o >>= 1) v = fmaxf(v, __shfl_down(v, o, 64));
  const int lane = threadIdx.x & 63, w = threadIdx.x >> 6;
  if (lane == 0) buf[w] = v;
  __syncthreads();
  float r = fmaxf(fmaxf(buf[0], buf[1]), fmaxf(buf[2], buf[3]));
  __syncthreads();
  return r;
}

__device__ __forceinline__ void lds16(const signed char* g, signed char* l) {
  __builtin_amdgcn_global_load_lds(
      (const __attribute__((address_space(1))) unsigned int*)g,
      (__attribute__((address_space(3))) unsigned int*)l, 16, 0, 0);
}

// ---------- weight abs-mean, both matrices in one dispatch ----------
__global__ __launch_bounds__(256) void absmean_partial2(const float* __restrict__ w1,
                                                        const float* __restrict__ w2,
                                                        int n, double* __restrict__ part1,
                                                        double* __restrict__ part2) {
  __shared__ float buf[4];
  const int half = gridDim.x >> 1;
  const bool second = (int)blockIdx.x >= half;
  const float* w = second ? w2 : w1;
  double* part = second ? part2 : part1;
  const int bid = second ? (blockIdx.x - half) : blockIdx.x;
  float s = 0.0f;
  const long stride = (long)half * 256 * 4;
  for (long i = ((long)bid * 256 + threadIdx.x) * 4; i < n; i += stride) {
    float4 v = *(const float4*)(w + i);
    s += fabsf(v.x) + fabsf(v.y) + fabsf(v.z) + fabsf(v.w);
  }
  float r = block_sum(s, buf);
  if (threadIdx.x == 0) part[bid] = (double)r;
}

__global__ __launch_bounds__(256) void absmean_final2(const double* __restrict__ part1,
                                                      const double* __restrict__ part2,
                                                      int nb, double n,
                                                      double* __restrict__ out) {
  __shared__ double buf[4];
  const double* part = (blockIdx.x == 0) ? part1 : part2;
  double s = 0.0;
  for (int i = threadIdx.x; i < nb; i += 256) s += part[i];
#pragma unroll
  for (int o = 32; o > 0; o >>= 1) s += __shfl_down(s, o, 64);
  const int lane = threadIdx.x & 63, w = threadIdx.x >> 6;
  if (lane == 0) buf[w] = s;
  __syncthreads();
  if (threadIdx.x == 0) out[blockIdx.x] = (buf[0] + buf[1] + buf[2] + buf[3]) / n;
}

// ---------- ternary weight quant -> i8 {-1,0,1}, both matrices ----------
__global__ __launch_bounds__(256) void wquant2_kernel(const float* __restrict__ w1,
                                                      const float* __restrict__ w2,
                                                      const double* __restrict__ means,
                                                      signed char* __restrict__ wq1,
                                                      signed char* __restrict__ wq2, int n) {
  const int half = gridDim.x >> 1;
  const bool second = (int)blockIdx.x >= half;
  const float* w = second ? w2 : w1;
  signed char* wq = second ? wq2 : wq1;
  const double mean = second ? means[1] : means[0];
  const int bid = second ? (blockIdx.x - half) : blockIdx.x;
  long i = ((long)bid * 256 + threadIdx.x) * 4;
  if (i >= n) return;
  const float s = 1.0f / (float)fmax(mean, 1e-5);
  float4 v = *(const float4*)(w + i);
  __align__(4) signed char q[4];
  q[0] = (signed char)(int)fminf(fmaxf(rintf(v.x * s), -1.f), 1.f);
  q[1] = (signed char)(int)fminf(fmaxf(rintf(v.y * s), -1.f), 1.f);
  q[2] = (signed char)(int)fminf(fmaxf(rintf(v.z * s), -1.f), 1.f);
  q[3] = (signed char)(int)fminf(fmaxf(rintf(v.w * s), -1.f), 1.f);
  *(int*)(wq + i) = *(int*)q;
}

// ---------- fused LayerNorm + per-token int8 absmax quant -> i8 ----------
__global__ __launch_bounds__(256) void ln_quant_kernel(const float* __restrict__ x,
                                                       const float* __restrict__ gamma,
                                                       const float* __restrict__ beta,
                                                       signed char* __restrict__ aq,
                                                       float* __restrict__ ds) {
  __shared__ float buf[4];
  const int t = threadIdx.x;
  const long row = blockIdx.x;
  const float* xr = x + row * (long)D_DIM;
  float v[8];
  *(float4*)(v)     = *(const float4*)(xr + t * 8);
  *(float4*)(v + 4) = *(const float4*)(xr + t * 8 + 4);
  float s = 0.f;
#pragma unroll
  for (int i = 0; i < 8; ++i) s += v[i];
  s = block_sum(s, buf);
  const float mu = s * (1.0f / 2048.0f);
  float sq = 0.f;
#pragma unroll
  for (int i = 0; i < 8; ++i) { float d = v[i] - mu; sq += d * d; }
  sq = block_sum(sq, buf);
  const float inv = 1.0f / sqrtf(sq * (1.0f / 2048.0f) + 1e-5f);
  float gam[8], bet[8];
  *(float4*)(gam)     = *(const float4*)(gamma + t * 8);
  *(float4*)(gam + 4) = *(const float4*)(gamma + t * 8 + 4);
  *(float4*)(bet)     = *(const float4*)(beta + t * 8);
  *(float4*)(bet + 4) = *(const float4*)(beta + t * 8 + 4);
  float xn[8]; float am = 0.f;
#pragma unroll
  for (int i = 0; i < 8; ++i) {
    xn[i] = (v[i] - mu) * inv * gam[i] + bet[i];
    am = fmaxf(am, fabsf(xn[i]));
  }
  am = block_max(am, buf);
  am = fmaxf(am, 1e-5f);
  const float qs = 127.0f / am;
  __align__(8) signed char q[8];
#pragma unroll
  for (int i = 0; i < 8; ++i)
    q[i] = (signed char)(int)fminf(fmaxf(rintf(xn[i] * qs), -128.f), 127.f);
  *(long*)(aq + row * D_DIM + t * 8) = *(long*)q;
  if (t == 0) ds[row] = am / 127.0f;
}

// ---------- per-token re-quant from f32 h chunk -> dense i8 ----------
__global__ __launch_bounds__(256) void hquant32_kernel(const float* __restrict__ src,
                                                       signed char* __restrict__ dst,
                                                       float* __restrict__ ds2) {
  __shared__ float buf[4];
  const int t = threadIdx.x;
  const long row = blockIdx.x;
  const float* sr = src + row * (long)H_DIM;
  float v[4][8];
#pragma unroll
  for (int c = 0; c < 4; ++c) {
    *(float4*)(v[c])     = *(const float4*)(sr + (c * 256 + t) * 8);
    *(float4*)(v[c] + 4) = *(const float4*)(sr + (c * 256 + t) * 8 + 4);
  }
  float am = 0.f;
#pragma unroll
  for (int c = 0; c < 4; ++c)
#pragma unroll
    for (int i = 0; i < 8; ++i) am = fmaxf(am, fabsf(v[c][i]));
  am = block_max(am, buf);
  am = fmaxf(am, 1e-5f);
  const float qs = 127.0f / am;
  signed char* dr = dst + row * (long)H_DIM;
#pragma unroll
  for (int c = 0; c < 4; ++c) {
    __align__(8) signed char o[8];
#pragma unroll
    for (int i = 0; i < 8; ++i)
      o[i] = (signed char)(int)fminf(fmaxf(rintf(v[c][i] * qs), -128.f), 127.f);
    *(long*)(dr + (c * 256 + t) * 8) = *(long*)o;
  }
  if (t == 0) ds2[row] = am / 127.0f;
}

// ---------- subtile readers / MFMA (i8, K=64 per instr) ----------
__device__ __forceinline__ void read_a2(const signed char* sm, int base, int4v (&af)[2]) {
#pragma unroll
  for (int ms = 0; ms < 2; ++ms)
    af[ms] = *(const int4v*)&sm[base + ms * 1024];   // 16 rows * 64B
}
__device__ __forceinline__ void read_b4(const signed char* sm, int base, int4v (&bf)[4]) {
#pragma unroll
  for (int ns = 0; ns < 4; ++ns)
    bf[ns] = *(const int4v*)&sm[base + ns * 1024];
}
__device__ __forceinline__ void mfma_half16(const int4v (&af)[2], const int4v (&bf)[4],
                                            int4v (&acc)[4][4], int m0) {
#pragma unroll
  for (int ms = 0; ms < 2; ++ms)
#pragma unroll
    for (int ns = 0; ns < 4; ++ns)
      acc[m0 + ms][ns] = __builtin_amdgcn_mfma_i32_16x16x64_i8(
          af[ms], bf[ns], acc[m0 + ms][ns], 0, 0, 0);
}

// ---------- 256x128 BK=64 i8 GEMM, triple-buffered A, 64x64 per wave ----------
// 8 waves (4M x 2N); LDS 64KB: A 3x16KB rotating, B 2x8KB ping-pong.
// R10 chunk-XOR swizzle both sides. Per K-tile, 2 phases:
//   Pa: read A-lo(cur)+B(curB); stage A(t+2)->aN2 (2 loads); BAR; lgkm0; MFMA m0-1
//   Pb: read A-hi(cur); stage B(t+2)->curB (1 load); BAR; lgkm0; MFMA m2-3;
//       vmcnt(3) [drains A(t+1)x2+B(t+1); leaves A(t+2)x2+B(t+2)]; BAR; rotate.
// A-stage lead = 4 phases (~1200cyc >= HBM latency); B lead = 2 phases (L2 wq).
// EPI==1: dequant+bias+exact GELU -> f32.  EPI==2: dequant+bias -> f32.
template <int EPI>
__global__ __launch_bounds__(512, 4) void gemm256_kernel(
    const signed char* __restrict__ A,
    const signed char* __restrict__ Bm,
    const float* __restrict__ dsA,
    const double* __restrict__ meanw,
    const float* __restrict__ bias,
    float* __restrict__ outf,
    int NBX, int N, int K) {
  __shared__ __align__(16) signed char smA[3 * 256 * 64];   // 48KB, 3 rotating bufs
  __shared__ __align__(16) signed char smB[2 * 128 * 64];   // 16KB, ping-pong
  const int tid = threadIdx.x;
  const int lane = tid & 63;
  const int wid = tid >> 6;
  const int wr = wid >> 1;    // 0..3 (M quarter: 64 rows)
  const int wcn = wid & 1;    // 0..1 (N half: 64 cols)

  // T1: XCD-aware bijective block swizzle (gridDim.x = 1024, %8==0)
  const int cpx = gridDim.x >> 3;
  const int swz = ((int)blockIdx.x & 7) * cpx + ((int)blockIdx.x >> 3);
  const int bx = swz % NBX, by = swz / NBX;
  const long r0 = (long)by * 256;
  const long c0 = (long)bx * 128;

  // staging geometry (R10): thread t -> row t>>2 (0..127), chunk (t&3)^swz(row).
  const int srow = tid >> 2;
  const int schunk = (tid & 3) ^ (srow & 3) ^ ((srow >> 2) & 3);
  const signed char* gAs = A + (r0 + srow) * (long)K + schunk * 16;
  const signed char* gBs = Bm + (c0 + srow) * (long)K + schunk * 16;

  // fragment-read geometry (R10): row base+frow, chunk (lane>>4)^swz(frow).
  const int frow = lane & 15;
  const int fchunk = (lane >> 4) ^ (frow & 3) ^ ((frow >> 2) & 3);
  const int fbyte = frow * 64 + fchunk * 16;
  // A: wave wr rows wr*64..+63 -> half wr>>1, sub-base (wr&1)*4096
  const int baseA = (wr >> 1) * 8192 + (wr & 1) * 4096 + fbyte;  // + abuf (+ms*1024)
  const int baseB = wcn * 4096 + fbyte;                          // + bbuf (+ns*1024)

  int4v acc[4][4] = {};
  int4v af[2], bf[4];
  const int nk = K >> 6;            // BK = 64 K-tiles

// stage A half h (128 rows) of K-tile t into A-buf at byte offset `off`
#define STGA(h, t, off)                                                       \
    lds16(gAs + (long)((h) * 128) * K + (long)(t) * 64,                       \
          &smA[(off) + (h) * 8192 + tid * 16]);
// stage B tile (128 rows) of K-tile t into B-buf at byte offset `off`
#define STGB(t, off)                                                          \
    lds16(gBs + (long)(t) * 64, &smB[(off) + tid * 16]);
#define BAR  __builtin_amdgcn_s_barrier()
#define SCB  __builtin_amdgcn_sched_barrier(0)
#define LGKM0 asm volatile("s_waitcnt lgkmcnt(0)" ::: "memory")
#define PRIO1 __builtin_amdgcn_s_setprio(1)
#define PRIO0 __builtin_amdgcn_s_setprio(0)

  // prologue: A(0)->buf0, B(0)->bbuf0, A(1)->buf1, B(1)->bbuf1.
  // Issue order {A0,A0,B0,A1,A1,B1}; vmcnt(3) drains A0x2+B0, leaves A1x2+B1.
  STGA(0, 0, 0); STGA(1, 0, 0); STGB(0, 0);
  STGA(0, 1, 16384); STGA(1, 1, 16384); STGB(1, 8192);
  asm volatile("s_waitcnt vmcnt(3)" ::: "memory");
  SCB; BAR; SCB;

  int aC = 0, aN = 16384, aN2 = 32768;  // A bufs for t, t+1, t+2 (byte offsets)
  int bC = 0;                           // B buf for t (toggles 8192)

  for (int t = 0; t < nk; ++t) {
    const bool s = (t + 2 < nk);

    // ---- Pa: read A-lo(cur)+B(cur); stage A(t+2)->aN2; MFMA m0-1
    read_a2(smA, aC + baseA, af);
    read_b4(smB, bC + baseB, bf);
    if (s) { STGA(0, t + 2, aN2); STGA(1, t + 2, aN2); }
    SCB; BAR; LGKM0; SCB;
    PRIO1; mfma_half16(af, bf, acc, 0); PRIO0;
    SCB; BAR;

    // ---- Pb: read A-hi(cur); stage B(t+2)->bC; MFMA m2-3; vmcnt; publish
    read_a2(smA, aC + baseA + 2048, af);
    if (s) STGB(t + 2, bC);
    SCB; BAR; LGKM0; SCB;
    PRIO1; mfma_half16(af, bf, acc, 2); PRIO0;
    SCB;
    if (s) { asm volatile("s_waitcnt vmcnt(3)" ::: "memory"); }  // A(t+1),B(t+1) landed
    else   { asm volatile("s_waitcnt vmcnt(0)" ::: "memory"); }
    SCB; BAR;

    // rotate buffers
    const int tmp = aC; aC = aN; aN = aN2; aN2 = tmp;
    bC ^= 8192;
  }
#undef STGA
#undef STGB
#undef BAR
#undef SCB
#undef LGKM0
#undef PRIO1
#undef PRIO0

  // ---- epilogue ----
  const float sw = (float)fmax(meanw[0], 1e-5);
#pragma unroll
  for (int m = 0; m < 4; ++m) {
#pragma unroll
    for (int j = 0; j < 4; ++j) {
      const long row = r0 + wr * 64 + m * 16 + (lane >> 4) * 4 + j;
      const float sa = dsA[row] * sw;
#pragma unroll
      for (int n = 0; n < 4; ++n) {
        const long col = c0 + wcn * 64 + n * 16 + (lane & 15);
        float v = (float)acc[m][n][j] * sa + bias[col];
        if (EPI == 1) {
          float gl = 0.5f * v * (1.0f + erff(v * 0.70710678118654752f));
          outf[row * (long)N + col] = gl;
        } else {
          outf[row * (long)N + col] = v;
        }
      }
    }
  }
}

extern "C" void kernel_launch(void* const* d_in, const int* in_sizes, int n_in,
                              void* d_out, int out_size, void* d_ws, size_t ws_size,
                              hipStream_t stream) {
  const float* x     = (const float*)d_in[0];
  const float* gamma = (const float*)d_in[1];
  const float* beta  = (const float*)d_in[2];
  const float* w1    = (const float*)d_in[3];
  const float* b1    = (const float*)d_in[4];
  const float* w2    = (const float*)d_in[5];
  const float* b2    = (const float*)d_in[6];

  char* ws = (char*)d_ws;
  // meta (<256K): part1@0, part2@16K, means@32K, ds1@64K, ds2@128K
  // [1M)        wq1 16M i8
  // [1M+16M)    wq2 16M i8
  // [1M+32M)    aq  32M i8
  // [1M+64M)    hq 128M i8
  // peak 193 MiB.  d_out (128M) doubles as f32 GELU staging per M-chunk.
  double* part1 = (double*)(ws + 0);
  double* part2 = (double*)(ws + 16384);
  double* means = (double*)(ws + 32768);
  float* ds1  = (float*)(ws + 65536);
  float* ds2  = (float*)(ws + 131072);
  signed char* wq1 = (signed char*)(ws + 1048576l);
  signed char* wq2 = (signed char*)(ws + 17825792l);
  signed char* aq  = (signed char*)(ws + 34603008l);
  signed char* hq  = (signed char*)(ws + 68157440l);

  const int NW = 16777216;  // elements in each weight matrix
  float* hstage = (float*)d_out;  // 4096 x 8192 f32 = 128 MiB, dead until GEMM2

  absmean_partial2<<<4096, 256, 0, stream>>>(w1, w2, NW, part1, part2);
  absmean_final2<<<2, 256, 0, stream>>>(part1, part2, 2048, (double)NW, means);
  wquant2_kernel<<<32768, 256, 0, stream>>>(w1, w2, means, wq1, wq2, NW);
  ln_quant_kernel<<<16384, 256, 0, stream>>>(x, gamma, beta, aq, ds1);

  // GEMM1 in 4 M-chunks: f32 gelu -> d_out staging, requant -> dense i8 hq
  for (int c = 0; c < 4; ++c) {
    const long r0 = (long)c * MCHUNK;
    gemm256_kernel<1><<<(H_DIM / 128) * (MCHUNK / 256), 512, 0, stream>>>(
        aq + r0 * D_DIM, wq1, ds1 + r0, means + 0, b1, hstage,
        H_DIM / 128, H_DIM, D_DIM);
    hquant32_kernel<<<MCHUNK, 256, 0, stream>>>(
        hstage, hq + r0 * H_DIM, ds2 + r0);
  }

  // GEMM2: out = hq . wq2^T * (ds2*sw2) + b2
  gemm256_kernel<2><<<(D_DIM / 128) * (M_DIM / 256), 512, 0, stream>>>(
      hq, wq2, ds2, means + 1, b2, (float*)d_out,
      D_DIM / 128, D_DIM, H_DIM);
}

// Round 22
// 859.343 us; speedup vs baseline: 1.0278x; 1.0278x over previous
//
#include <hip/hip_runtime.h>
#include <hip/hip_bf16.h>

// BitNet FFN: LN -> act_quant/ternary-W matmul -> GELU(erf) -> act_quant/ternary-W matmul
// Shapes: x[4,4096,2048] f32, w1[8192,2048], w2[2048,8192], out [16384,2048] f32.
// R22: single-barrier K-tile at 4 waves/SIMD (R14's schedule x R19's occupancy).
// R14's 1-barrier loop failed at 2 w/SIMD (exposed lgkm latency, no TLP);
// R19-21 have 4 w/SIMD but 4 barriers/K-tile re-lock waves every ~200cyc.
// Now: {8 ds_reads -> lgkm(2) -> 8 MFMA -> lgkm(0) -> 8 MFMA -> vmcnt(3) ->
// ONE barrier}. B triple-buffered (A 3x16K + B 3x8K = 72KB, 2 blocks/CU) so
// stages target the buffer read 3 iters ago (WAR behind prev barrier).
// Single-queue vmcnt(3) ledger (3 stages/iter, steady in-flight 6).
// i8 MFMA 16x16x64; i32 accum exact -> output bit-identical (absmax 2.539e-2).
// Peak ws 193 MiB; d_out doubles as f32 GELU staging per M-chunk.

typedef __attribute__((ext_vector_type(4))) int int4v;

#define D_DIM 2048
#define H_DIM 8192
#define M_DIM 16384
#define MCHUNK 4096

// ---------- small helpers ----------
__device__ __forceinline__ float block_sum(float v, float* buf) {
#pragma unroll
  for (int o = 32; o > 0; o >>= 1) v += __shfl_down(v, o, 64);
  const int lane = threadIdx.x & 63, w = threadIdx.x >> 6;
  if (lane == 0) buf[w] = v;
  __syncthreads();
  float r = buf[0] + buf[1] + buf[2] + buf[3];
  __syncthreads();
  return r;
}
__device__ __forceinline__ float block_max(float v, float* buf) {
#pragma unroll
  for (int o = 32; o > 0; o >>= 1) v = fmaxf(v, __shfl_down(v, o, 64));
  const int lane = threadIdx.x & 63, w = threadIdx.x >> 6;
  if (lane == 0) buf[w] = v;
  __syncthreads();
  float r = fmaxf(fmaxf(buf[0], buf[1]), fmaxf(buf[2], buf[3]));
  __syncthreads();
  return r;
}

__device__ __forceinline__ void lds16(const signed char* g, signed char* l) {
  __builtin_amdgcn_global_load_lds(
      (const __attribute__((address_space(1))) unsigned int*)g,
      (__attribute__((address_space(3))) unsigned int*)l, 16, 0, 0);
}

// ---------- weight abs-mean, both matrices in one dispatch ----------
__global__ __launch_bounds__(256) void absmean_partial2(const float* __restrict__ w1,
                                                        const float* __restrict__ w2,
                                                        int n, double* __restrict__ part1,
                                                        double* __restrict__ part2) {
  __shared__ float buf[4];
  const int half = gridDim.x >> 1;
  const bool second = (int)blockIdx.x >= half;
  const float* w = second ? w2 : w1;
  double* part = second ? part2 : part1;
  const int bid = second ? (blockIdx.x - half) : blockIdx.x;
  float s = 0.0f;
  const long stride = (long)half * 256 * 4;
  for (long i = ((long)bid * 256 + threadIdx.x) * 4; i < n; i += stride) {
    float4 v = *(const float4*)(w + i);
    s += fabsf(v.x) + fabsf(v.y) + fabsf(v.z) + fabsf(v.w);
  }
  float r = block_sum(s, buf);
  if (threadIdx.x == 0) part[bid] = (double)r;
}

__global__ __launch_bounds__(256) void absmean_final2(const double* __restrict__ part1,
                                                      const double* __restrict__ part2,
                                                      int nb, double n,
                                                      double* __restrict__ out) {
  __shared__ double buf[4];
  const double* part = (blockIdx.x == 0) ? part1 : part2;
  double s = 0.0;
  for (int i = threadIdx.x; i < nb; i += 256) s += part[i];
#pragma unroll
  for (int o = 32; o > 0; o >>= 1) s += __shfl_down(s, o, 64);
  const int lane = threadIdx.x & 63, w = threadIdx.x >> 6;
  if (lane == 0) buf[w] = s;
  __syncthreads();
  if (threadIdx.x == 0) out[blockIdx.x] = (buf[0] + buf[1] + buf[2] + buf[3]) / n;
}

// ---------- ternary weight quant -> i8 {-1,0,1}, both matrices ----------
__global__ __launch_bounds__(256) void wquant2_kernel(const float* __restrict__ w1,
                                                      const float* __restrict__ w2,
                                                      const double* __restrict__ means,
                                                      signed char* __restrict__ wq1,
                                                      signed char* __restrict__ wq2, int n) {
  const int half = gridDim.x >> 1;
  const bool second = (int)blockIdx.x >= half;
  const float* w = second ? w2 : w1;
  signed char* wq = second ? wq2 : wq1;
  const double mean = second ? means[1] : means[0];
  const int bid = second ? (blockIdx.x - half) : blockIdx.x;
  long i = ((long)bid * 256 + threadIdx.x) * 4;
  if (i >= n) return;
  const float s = 1.0f / (float)fmax(mean, 1e-5);
  float4 v = *(const float4*)(w + i);
  __align__(4) signed char q[4];
  q[0] = (signed char)(int)fminf(fmaxf(rintf(v.x * s), -1.f), 1.f);
  q[1] = (signed char)(int)fminf(fmaxf(rintf(v.y * s), -1.f), 1.f);
  q[2] = (signed char)(int)fminf(fmaxf(rintf(v.z * s), -1.f), 1.f);
  q[3] = (signed char)(int)fminf(fmaxf(rintf(v.w * s), -1.f), 1.f);
  *(int*)(wq + i) = *(int*)q;
}

// ---------- fused LayerNorm + per-token int8 absmax quant -> i8 ----------
__global__ __launch_bounds__(256) void ln_quant_kernel(const float* __restrict__ x,
                                                       const float* __restrict__ gamma,
                                                       const float* __restrict__ beta,
                                                       signed char* __restrict__ aq,
                                                       float* __restrict__ ds) {
  __shared__ float buf[4];
  const int t = threadIdx.x;
  const long row = blockIdx.x;
  const float* xr = x + row * (long)D_DIM;
  float v[8];
  *(float4*)(v)     = *(const float4*)(xr + t * 8);
  *(float4*)(v + 4) = *(const float4*)(xr + t * 8 + 4);
  float s = 0.f;
#pragma unroll
  for (int i = 0; i < 8; ++i) s += v[i];
  s = block_sum(s, buf);
  const float mu = s * (1.0f / 2048.0f);
  float sq = 0.f;
#pragma unroll
  for (int i = 0; i < 8; ++i) { float d = v[i] - mu; sq += d * d; }
  sq = block_sum(sq, buf);
  const float inv = 1.0f / sqrtf(sq * (1.0f / 2048.0f) + 1e-5f);
  float gam[8], bet[8];
  *(float4*)(gam)     = *(const float4*)(gamma + t * 8);
  *(float4*)(gam + 4) = *(const float4*)(gamma + t * 8 + 4);
  *(float4*)(bet)     = *(const float4*)(beta + t * 8);
  *(float4*)(bet + 4) = *(const float4*)(beta + t * 8 + 4);
  float xn[8]; float am = 0.f;
#pragma unroll
  for (int i = 0; i < 8; ++i) {
    xn[i] = (v[i] - mu) * inv * gam[i] + bet[i];
    am = fmaxf(am, fabsf(xn[i]));
  }
  am = block_max(am, buf);
  am = fmaxf(am, 1e-5f);
  const float qs = 127.0f / am;
  __align__(8) signed char q[8];
#pragma unroll
  for (int i = 0; i < 8; ++i)
    q[i] = (signed char)(int)fminf(fmaxf(rintf(xn[i] * qs), -128.f), 127.f);
  *(long*)(aq + row * D_DIM + t * 8) = *(long*)q;
  if (t == 0) ds[row] = am / 127.0f;
}

// ---------- per-token re-quant from f32 h chunk -> dense i8 ----------
__global__ __launch_bounds__(256) void hquant32_kernel(const float* __restrict__ src,
                                                       signed char* __restrict__ dst,
                                                       float* __restrict__ ds2) {
  __shared__ float buf[4];
  const int t = threadIdx.x;
  const long row = blockIdx.x;
  const float* sr = src + row * (long)H_DIM;
  float v[4][8];
#pragma unroll
  for (int c = 0; c < 4; ++c) {
    *(float4*)(v[c])     = *(const float4*)(sr + (c * 256 + t) * 8);
    *(float4*)(v[c] + 4) = *(const float4*)(sr + (c * 256 + t) * 8 + 4);
  }
  float am = 0.f;
#pragma unroll
  for (int c = 0; c < 4; ++c)
#pragma unroll
    for (int i = 0; i < 8; ++i) am = fmaxf(am, fabsf(v[c][i]));
  am = block_max(am, buf);
  am = fmaxf(am, 1e-5f);
  const float qs = 127.0f / am;
  signed char* dr = dst + row * (long)H_DIM;
#pragma unroll
  for (int c = 0; c < 4; ++c) {
    __align__(8) signed char o[8];
#pragma unroll
    for (int i = 0; i < 8; ++i)
      o[i] = (signed char)(int)fminf(fmaxf(rintf(v[c][i] * qs), -128.f), 127.f);
    *(long*)(dr + (c * 256 + t) * 8) = *(long*)o;
  }
  if (t == 0) ds2[row] = am / 127.0f;
}

// ---------- subtile readers / MFMA (i8, K=64 per instr) ----------
__device__ __forceinline__ void read_a2(const signed char* sm, int base, int4v (&af)[2]) {
#pragma unroll
  for (int ms = 0; ms < 2; ++ms)
    af[ms] = *(const int4v*)&sm[base + ms * 1024];   // 16 rows * 64B
}
__device__ __forceinline__ void read_b4(const signed char* sm, int base, int4v (&bf)[4]) {
#pragma unroll
  for (int ns = 0; ns < 4; ++ns)
    bf[ns] = *(const int4v*)&sm[base + ns * 1024];
}
__device__ __forceinline__ void mfma_half16(const int4v (&af)[2], const int4v (&bf)[4],
                                            int4v (&acc)[4][4], int m0) {
#pragma unroll
  for (int ms = 0; ms < 2; ++ms)
#pragma unroll
    for (int ns = 0; ns < 4; ++ns)
      acc[m0 + ms][ns] = __builtin_amdgcn_mfma_i32_16x16x64_i8(
          af[ms], bf[ns], acc[m0 + ms][ns], 0, 0, 0);
}

// ---------- 256x128 BK=64 i8 GEMM, triple-buffered A+B, 64x64 per wave ----------
// 8 waves (4M x 2N), 4 waves/SIMD (launch_bounds(512,4)); LDS 72KB
// (A 3x16KB + B 3x8KB rotating) -> 2 blocks/CU, 16 waves/CU.
// R10 chunk-XOR swizzle both sides. ONE barrier per K-tile:
//   {read A-lo,B,A-hi (8 ds); stage A(t+2),B(t+2) -> 3-ago bufs; lgkm(2);
//    MFMA m0-1; lgkm(0); MFMA m2-3; vmcnt(3); BAR; rotate}
// Stalled waves are covered by 3 sibling waves/SIMD (TLP; R14 lacked this).
// EPI==1: dequant+bias+exact GELU -> f32.  EPI==2: dequant+bias -> f32.
template <int EPI>
__global__ __launch_bounds__(512, 4) void gemm256_kernel(
    const signed char* __restrict__ A,
    const signed char* __restrict__ Bm,
    const float* __restrict__ dsA,
    const double* __restrict__ meanw,
    const float* __restrict__ bias,
    float* __restrict__ outf,
    int NBX, int N, int K) {
  __shared__ __align__(16) signed char smA[3 * 256 * 64];   // 48KB, 3 rotating bufs
  __shared__ __align__(16) signed char smB[3 * 128 * 64];   // 24KB, 3 rotating bufs
  const int tid = threadIdx.x;
  const int lane = tid & 63;
  const int wid = tid >> 6;
  const int wr = wid >> 1;    // 0..3 (M quarter: 64 rows)
  const int wcn = wid & 1;    // 0..1 (N half: 64 cols)

  // T1: XCD-aware bijective block swizzle (gridDim.x = 1024, %8==0)
  const int cpx = gridDim.x >> 3;
  const int swz = ((int)blockIdx.x & 7) * cpx + ((int)blockIdx.x >> 3);
  const int bx = swz % NBX, by = swz / NBX;
  const long r0 = (long)by * 256;
  const long c0 = (long)bx * 128;

  // staging geometry (R10): thread t -> row t>>2 (0..127), chunk (t&3)^swz(row).
  const int srow = tid >> 2;
  const int schunk = (tid & 3) ^ (srow & 3) ^ ((srow >> 2) & 3);
  const signed char* gAs = A + (r0 + srow) * (long)K + schunk * 16;
  const signed char* gBs = Bm + (c0 + srow) * (long)K + schunk * 16;

  // fragment-read geometry (R10): row base+frow, chunk (lane>>4)^swz(frow).
  const int frow = lane & 15;
  const int fchunk = (lane >> 4) ^ (frow & 3) ^ ((frow >> 2) & 3);
  const int fbyte = frow * 64 + fchunk * 16;
  // A: wave wr rows wr*64..+63 -> half wr>>1, sub-base (wr&1)*4096
  const int baseA = (wr >> 1) * 8192 + (wr & 1) * 4096 + fbyte;  // + abuf (+ms*1024)
  const int baseB = wcn * 4096 + fbyte;                          // + bbuf (+ns*1024)

  int4v acc[4][4] = {};
  int4v afLo[2], afHi[2], bf[4];
  const int nk = K >> 6;            // BK = 64 K-tiles

// stage A half h (128 rows) of K-tile t into A-buf at byte offset `off`
#define STGA(h, t, off)                                                       \
    lds16(gAs + (long)((h) * 128) * K + (long)(t) * 64,                       \
          &smA[(off) + (h) * 8192 + tid * 16]);
// stage B tile (128 rows) of K-tile t into B-buf at byte offset `off`
#define STGB(t, off)                                                          \
    lds16(gBs + (long)(t) * 64, &smB[(off) + tid * 16]);
#define BAR  __builtin_amdgcn_s_barrier()
#define SCB  __builtin_amdgcn_sched_barrier(0)
#define PRIO1 __builtin_amdgcn_s_setprio(1)
#define PRIO0 __builtin_amdgcn_s_setprio(0)

  // prologue: {A(0)x2,B(0)} -> bufs0, {A(1)x2,B(1)} -> bufs1.
  // vmcnt(3) drains t0's 3 loads, leaves t1's 3 in flight.
  STGA(0, 0, 0); STGA(1, 0, 0); STGB(0, 0);
  STGA(0, 1, 16384); STGA(1, 1, 16384); STGB(1, 8192);
  asm volatile("s_waitcnt vmcnt(3)" ::: "memory");
  SCB; BAR; SCB;

  int aC = 0, aN = 16384, aN2 = 32768;  // A bufs for t, t+1, t+2 (byte offsets)
  int bC = 0, bN = 8192, bN2 = 16384;   // B bufs for t, t+1, t+2

  for (int t = 0; t < nk; ++t) {
    const bool s = (t + 2 < nk);

    // issue all 8 subtile reads (order: A-lo x2, B x4, A-hi x2)
    read_a2(smA, aC + baseA, afLo);
    read_b4(smB, bC + baseB, bf);
    read_a2(smA, aC + baseA + 2048, afHi);
    // stage t+2 into the buffers read 3 iterations ago (WAR behind prev BAR)
    if (s) { STGA(0, t + 2, aN2); STGA(1, t + 2, aN2); STGB(t + 2, bN2); }
    SCB;
    // A-lo + B landed (in-order DS retire; <=2 outstanding = A-hi)
    asm volatile("s_waitcnt lgkmcnt(2)" ::: "memory"); SCB;
    PRIO1; mfma_half16(afLo, bf, acc, 0); PRIO0; SCB;
    // A-hi landed
    asm volatile("s_waitcnt lgkmcnt(0)" ::: "memory"); SCB;
    PRIO1; mfma_half16(afHi, bf, acc, 2); PRIO0; SCB;
    // t+1's 3 loads landed (leave t+2's 3 in flight); publish
    if (s) { asm volatile("s_waitcnt vmcnt(3)" ::: "memory"); }
    else   { asm volatile("s_waitcnt vmcnt(0)" ::: "memory"); }
    SCB; BAR; SCB;

    // rotate buffers (period 3)
    int tmp = aC; aC = aN; aN = aN2; aN2 = tmp;
    tmp = bC; bC = bN; bN = bN2; bN2 = tmp;
  }
#undef STGA
#undef STGB
#undef BAR
#undef SCB
#undef PRIO1
#undef PRIO0

  // ---- epilogue ----
  const float sw = (float)fmax(meanw[0], 1e-5);
#pragma unroll
  for (int m = 0; m < 4; ++m) {
#pragma unroll
    for (int j = 0; j < 4; ++j) {
      const long row = r0 + wr * 64 + m * 16 + (lane >> 4) * 4 + j;
      const float sa = dsA[row] * sw;
#pragma unroll
      for (int n = 0; n < 4; ++n) {
        const long col = c0 + wcn * 64 + n * 16 + (lane & 15);
        float v = (float)acc[m][n][j] * sa + bias[col];
        if (EPI == 1) {
          float gl = 0.5f * v * (1.0f + erff(v * 0.70710678118654752f));
          outf[row * (long)N + col] = gl;
        } else {
          outf[row * (long)N + col] = v;
        }
      }
    }
  }
}

extern "C" void kernel_launch(void* const* d_in, const int* in_sizes, int n_in,
                              void* d_out, int out_size, void* d_ws, size_t ws_size,
                              hipStream_t stream) {
  const float* x     = (const float*)d_in[0];
  const float* gamma = (const float*)d_in[1];
  const float* beta  = (const float*)d_in[2];
  const float* w1    = (const float*)d_in[3];
  const float* b1    = (const float*)d_in[4];
  const float* w2    = (const float*)d_in[5];
  const float* b2    = (const float*)d_in[6];

  char* ws = (char*)d_ws;
  // meta (<256K): part1@0, part2@16K, means@32K, ds1@64K, ds2@128K
  // [1M)        wq1 16M i8
  // [1M+16M)    wq2 16M i8
  // [1M+32M)    aq  32M i8
  // [1M+64M)    hq 128M i8
  // peak 193 MiB.  d_out (128M) doubles as f32 GELU staging per M-chunk.
  double* part1 = (double*)(ws + 0);
  double* part2 = (double*)(ws + 16384);
  double* means = (double*)(ws + 32768);
  float* ds1  = (float*)(ws + 65536);
  float* ds2  = (float*)(ws + 131072);
  signed char* wq1 = (signed char*)(ws + 1048576l);
  signed char* wq2 = (signed char*)(ws + 17825792l);
  signed char* aq  = (signed char*)(ws + 34603008l);
  signed char* hq  = (signed char*)(ws + 68157440l);

  const int NW = 16777216;  // elements in each weight matrix
  float* hstage = (float*)d_out;  // 4096 x 8192 f32 = 128 MiB, dead until GEMM2

  absmean_partial2<<<4096, 256, 0, stream>>>(w1, w2, NW, part1, part2);
  absmean_final2<<<2, 256, 0, stream>>>(part1, part2, 2048, (double)NW, means);
  wquant2_kernel<<<32768, 256, 0, stream>>>(w1, w2, means, wq1, wq2, NW);
  ln_quant_kernel<<<16384, 256, 0, stream>>>(x, gamma, beta, aq, ds1);

  // GEMM1 in 4 M-chunks: f32 gelu -> d_out staging, requant -> dense i8 hq
  for (int c = 0; c < 4; ++c) {
    const long r0 = (long)c * MCHUNK;
    gemm256_kernel<1><<<(H_DIM / 128) * (MCHUNK / 256), 512, 0, stream>>>(
        aq + r0 * D_DIM, wq1, ds1 + r0, means + 0, b1, hstage,
        H_DIM / 128, H_DIM, D_DIM);
    hquant32_kernel<<<MCHUNK, 256, 0, stream>>>(
        hstage, hq + r0 * H_DIM, ds2 + r0);
  }

  // GEMM2: out = hq . wq2^T * (ds2*sw2) + b2
  gemm256_kernel<2><<<(D_DIM / 128) * (M_DIM / 256), 512, 0, stream>>>(
      hq, wq2, ds2, means + 1, b2, (float*)d_out,
      D_DIM / 128, D_DIM, H_DIM);
}